// Round 1
// baseline (249.542 us; speedup 1.0000x reference)
//
#include <hip/hip_runtime.h>

#define DM   768
#define HN   12
#define DKH  64
#define BSZ  2
#define SEQ  2048
#define MROWS (BSZ*SEQ)   // 4096
#define NEGBIG -1.0e9f

typedef __bf16 bf16;
typedef __bf16 bf16x8 __attribute__((ext_vector_type(8)));
typedef __bf16 bf16x4 __attribute__((ext_vector_type(4)));
typedef float  f32x4  __attribute__((ext_vector_type(4)));

__device__ __forceinline__ void gload_lds16(const void* g, void* l) {
    __builtin_amdgcn_global_load_lds(
        (const __attribute__((address_space(1))) char*)g,
        (__attribute__((address_space(3))) char*)l, 16, 0, 0);
}

// ---------------- fp32 -> bf16 convert ----------------
__global__ __launch_bounds__(256) void cvt_kernel(const float* __restrict__ s,
                                                  bf16* __restrict__ d, int n) {
    int i = (blockIdx.x * 256 + threadIdx.x) * 4;
    if (i + 3 < n) {
        const float4* sp = (const float4*)(s + i);
        float4 v = *sp;
        bf16x4 o;
        o[0] = (bf16)v.x; o[1] = (bf16)v.y; o[2] = (bf16)v.z; o[3] = (bf16)v.w;
        *(bf16x4*)(d + i) = o;
    }
}

// ---------------- QKV projection GEMM (m97 structure) ----------------
// C[m,e] = sum_d X[m,d] * W[e,d]   (NT layout), output scattered to [B,H,S,64] bf16
__global__ __launch_bounds__(256) void gemm_qkv(
    const bf16* __restrict__ xq, const bf16* __restrict__ xk, const bf16* __restrict__ xv,
    const bf16* __restrict__ wq, const bf16* __restrict__ wk, const bf16* __restrict__ wv,
    bf16* __restrict__ qh, bf16* __restrict__ kh, bf16* __restrict__ vh)
{
    __shared__ bf16 As[128 * 32];
    __shared__ bf16 Bs[128 * 32];

    const bf16* A; const bf16* Bw; bf16* Out;
    if      (blockIdx.z == 0) { A = xq; Bw = wq; Out = qh; }
    else if (blockIdx.z == 1) { A = xk; Bw = wk; Out = kh; }
    else                      { A = xv; Bw = wv; Out = vh; }

    const int t = threadIdx.x, w = t >> 6, lane = t & 63;
    const int mt = blockIdx.x * 128, nt = blockIdx.y * 128;
    const int wr = (w >> 1) * 64, wc = (w & 1) * 64;

    f32x4 acc[4][4] = {};

    for (int k0 = 0; k0 < DM; k0 += 32) {
        #pragma unroll
        for (int i = 0; i < 2; i++) {
            int c = i * 256 + t;          // 16B chunk index
            int row = c >> 2, col = (c & 3) * 8;
            gload_lds16(A  + (size_t)(mt + row) * DM + k0 + col, (char*)As + c * 16);
            gload_lds16(Bw + (size_t)(nt + row) * DM + k0 + col, (char*)Bs + c * 16);
        }
        asm volatile("s_waitcnt vmcnt(0)" ::: "memory");
        __syncthreads();

        bf16x8 af[4], bfr[4];
        #pragma unroll
        for (int m = 0; m < 4; m++)
            af[m] = *(const bf16x8*)&As[(wr + m * 16 + (lane & 15)) * 32 + (lane >> 4) * 8];
        #pragma unroll
        for (int n = 0; n < 4; n++)
            bfr[n] = *(const bf16x8*)&Bs[(wc + n * 16 + (lane & 15)) * 32 + (lane >> 4) * 8];
        #pragma unroll
        for (int m = 0; m < 4; m++)
            #pragma unroll
            for (int n = 0; n < 4; n++)
                acc[m][n] = __builtin_amdgcn_mfma_f32_16x16x32_bf16(af[m], bfr[n], acc[m][n], 0, 0, 0);
        __syncthreads();
    }

    // scatter to [B,H,S,64]
    #pragma unroll
    for (int m = 0; m < 4; m++) {
        #pragma unroll
        for (int n = 0; n < 4; n++) {
            #pragma unroll
            for (int r = 0; r < 4; r++) {
                int gm = mt + wr + m * 16 + (lane >> 4) * 4 + r;   // row in [0,4096)
                int gn = nt + wc + n * 16 + (lane & 15);            // col in [0,768)
                int b = gm >> 11, s = gm & 2047, h = gn >> 6, d = gn & 63;
                Out[(((size_t)b * HN + h) * SEQ + s) * DKH + d] = (bf16)acc[m][n][r];
            }
        }
    }
}

// ---------------- output projection GEMM: out = ctx @ Wo^T (fp32 out) ----------------
__global__ __launch_bounds__(256) void gemm_out(
    const bf16* __restrict__ Actx, const bf16* __restrict__ Bw, float* __restrict__ Out)
{
    __shared__ bf16 As[128 * 32];
    __shared__ bf16 Bs[128 * 32];

    const int t = threadIdx.x, w = t >> 6, lane = t & 63;
    const int mt = blockIdx.x * 128, nt = blockIdx.y * 128;
    const int wr = (w >> 1) * 64, wc = (w & 1) * 64;

    f32x4 acc[4][4] = {};

    for (int k0 = 0; k0 < DM; k0 += 32) {
        #pragma unroll
        for (int i = 0; i < 2; i++) {
            int c = i * 256 + t;
            int row = c >> 2, col = (c & 3) * 8;
            gload_lds16(Actx + (size_t)(mt + row) * DM + k0 + col, (char*)As + c * 16);
            gload_lds16(Bw   + (size_t)(nt + row) * DM + k0 + col, (char*)Bs + c * 16);
        }
        asm volatile("s_waitcnt vmcnt(0)" ::: "memory");
        __syncthreads();

        bf16x8 af[4], bfr[4];
        #pragma unroll
        for (int m = 0; m < 4; m++)
            af[m] = *(const bf16x8*)&As[(wr + m * 16 + (lane & 15)) * 32 + (lane >> 4) * 8];
        #pragma unroll
        for (int n = 0; n < 4; n++)
            bfr[n] = *(const bf16x8*)&Bs[(wc + n * 16 + (lane & 15)) * 32 + (lane >> 4) * 8];
        #pragma unroll
        for (int m = 0; m < 4; m++)
            #pragma unroll
            for (int n = 0; n < 4; n++)
                acc[m][n] = __builtin_amdgcn_mfma_f32_16x16x32_bf16(af[m], bfr[n], acc[m][n], 0, 0, 0);
        __syncthreads();
    }

    #pragma unroll
    for (int m = 0; m < 4; m++) {
        #pragma unroll
        for (int n = 0; n < 4; n++) {
            #pragma unroll
            for (int r = 0; r < 4; r++) {
                int gm = mt + wr + m * 16 + (lane >> 4) * 4 + r;
                int gn = nt + wc + n * 16 + (lane & 15);
                Out[(size_t)gm * DM + gn] = acc[m][n][r];
            }
        }
    }
}

// ---------------- causal flash attention ----------------
// grid (SEQ/64, B*H). 4 waves/block; wave w owns Q rows [qb+16w, qb+16w+16).
__global__ __launch_bounds__(256) void flash_attn(
    const bf16* __restrict__ qh, const bf16* __restrict__ kh,
    const bf16* __restrict__ vh, bf16* __restrict__ ctx)
{
    const int qb = blockIdx.x * 64;
    const int bh = blockIdx.y;
    const int t = threadIdx.x, w = t >> 6, lane = t & 63;
    const size_t base = (size_t)bh * SEQ * DKH;

    __shared__ bf16 vt[64 * 40];        // V^T [d][key], padded stride 40
    __shared__ bf16 pl[4 * 16 * 40];    // per-wave P [16][40]

    // Q fragments (K=0..31, 32..63)
    const int qrow_frag = qb + w * 16 + (lane & 15);
    const bf16* qp = qh + base + (size_t)qrow_frag * DKH + (lane >> 4) * 8;
    bf16x8 q0 = *(const bf16x8*)qp;
    bf16x8 q1 = *(const bf16x8*)(qp + 32);

    f32x4 O[4] = {};
    float m_old[4], l_run[4];
    int qi[4];
    #pragma unroll
    for (int r = 0; r < 4; r++) {
        m_old[r] = -1e30f; l_run[r] = 0.0f;
        qi[r] = qb + w * 16 + (lane >> 4) * 4 + r;
    }

    const int ktiles = (qb + 64) / 32;
    for (int it = 0; it < ktiles; ++it) {
        const int kt = it * 32;
        __syncthreads();   // vt reuse guard
        {   // stage V transposed: 256 threads x 8 elems
            int key = t >> 3, d0 = (t & 7) * 8;
            bf16x8 vv = *(const bf16x8*)(vh + base + (size_t)(kt + key) * DKH + d0);
            #pragma unroll
            for (int j = 0; j < 8; j++) vt[(d0 + j) * 40 + key] = vv[j];
        }
        __syncthreads();

        // ---- QK^T: 16 q-rows x 32 keys ----
        f32x4 s[2];
        #pragma unroll
        for (int cg = 0; cg < 2; cg++) {
            const bf16* kp = kh + base + (size_t)(kt + cg * 16 + (lane & 15)) * DKH + (lane >> 4) * 8;
            bf16x8 kf0 = *(const bf16x8*)kp;
            bf16x8 kf1 = *(const bf16x8*)(kp + 32);
            f32x4 z = {0.0f, 0.0f, 0.0f, 0.0f};
            z = __builtin_amdgcn_mfma_f32_16x16x32_bf16(q0, kf0, z, 0, 0, 0);
            z = __builtin_amdgcn_mfma_f32_16x16x32_bf16(q1, kf1, z, 0, 0, 0);
            s[cg] = z;
        }
        // scale + causal mask
        #pragma unroll
        for (int cg = 0; cg < 2; cg++) {
            int ki = kt + cg * 16 + (lane & 15);
            #pragma unroll
            for (int r = 0; r < 4; r++) {
                float v = s[cg][r] * 0.125f;
                s[cg][r] = (ki > qi[r]) ? NEGBIG : v;
            }
        }
        // row max across the 16-lane col group
        float mt_[4];
        #pragma unroll
        for (int r = 0; r < 4; r++) mt_[r] = fmaxf(s[0][r], s[1][r]);
        #pragma unroll
        for (int msk = 1; msk < 16; msk <<= 1)
            #pragma unroll
            for (int r = 0; r < 4; r++) mt_[r] = fmaxf(mt_[r], __shfl_xor(mt_[r], msk, 64));

        float mnew[4], scl[4], e0[4], e1[4], rs[4];
        #pragma unroll
        for (int r = 0; r < 4; r++) {
            mnew[r] = fmaxf(m_old[r], mt_[r]);
            scl[r]  = __expf(m_old[r] - mnew[r]);
            e0[r]   = __expf(s[0][r] - mnew[r]);
            e1[r]   = __expf(s[1][r] - mnew[r]);
            rs[r]   = e0[r] + e1[r];
        }
        #pragma unroll
        for (int msk = 1; msk < 16; msk <<= 1)
            #pragma unroll
            for (int r = 0; r < 4; r++) rs[r] += __shfl_xor(rs[r], msk, 64);
        #pragma unroll
        for (int r = 0; r < 4; r++) {
            l_run[r] = l_run[r] * scl[r] + rs[r];
            m_old[r] = mnew[r];
        }
        #pragma unroll
        for (int dg = 0; dg < 4; dg++)
            #pragma unroll
            for (int r = 0; r < 4; r++) O[dg][r] *= scl[r];

        // P -> LDS (C-frag layout -> A-frag layout relayout)
        const int pbase = w * 16 * 40;
        #pragma unroll
        for (int r = 0; r < 4; r++) {
            int prow = (lane >> 4) * 4 + r;
            pl[pbase + prow * 40 + (lane & 15)]      = (bf16)e0[r];
            pl[pbase + prow * 40 + 16 + (lane & 15)] = (bf16)e1[r];
        }
        asm volatile("s_waitcnt lgkmcnt(0)" ::: "memory");

        // ---- PV ----
        bf16x8 pa = *(const bf16x8*)&pl[pbase + (lane & 15) * 40 + (lane >> 4) * 8];
        #pragma unroll
        for (int dg = 0; dg < 4; dg++) {
            bf16x8 vb = *(const bf16x8*)&vt[(dg * 16 + (lane & 15)) * 40 + (lane >> 4) * 8];
            O[dg] = __builtin_amdgcn_mfma_f32_16x16x32_bf16(pa, vb, O[dg], 0, 0, 0);
        }
    }

    // epilogue: normalize, store ctx [B,S,768] bf16
    float inv[4];
    #pragma unroll
    for (int r = 0; r < 4; r++) inv[r] = 1.0f / l_run[r];
    const int b = bh / HN, h = bh % HN;
    #pragma unroll
    for (int dg = 0; dg < 4; dg++) {
        #pragma unroll
        for (int r = 0; r < 4; r++) {
            int row = qb + w * 16 + (lane >> 4) * 4 + r;
            ctx[((size_t)(b * SEQ + row)) * DM + h * DKH + dg * 16 + (lane & 15)] =
                (bf16)(O[dg][r] * inv[r]);
        }
    }
}

// ---------------- launch ----------------
extern "C" void kernel_launch(void* const* d_in, const int* in_sizes, int n_in,
                              void* d_out, int out_size, void* d_ws, size_t ws_size,
                              hipStream_t stream) {
    const float* q  = (const float*)d_in[0];
    const float* k  = (const float*)d_in[1];
    const float* v  = (const float*)d_in[2];
    // d_in[3] = mask (static causal tril) — unused
    const float* wq = (const float*)d_in[4];
    const float* wk = (const float*)d_in[5];
    const float* wv = (const float*)d_in[6];
    const float* wo = (const float*)d_in[7];
    float* out = (float*)d_out;

    const size_t NX = (size_t)MROWS * DM;   // 3145728
    const size_t NW = (size_t)DM * DM;      // 589824

    bf16* p = (bf16*)d_ws;
    bf16* xq  = p; p += NX;
    bf16* xk  = p; p += NX;
    bf16* xv  = p; p += NX;
    bf16* wqb = p; p += NW;
    bf16* wkb = p; p += NW;
    bf16* wvb = p; p += NW;
    bf16* wob = p; p += NW;
    bf16* qhp = p; p += NX;
    bf16* khp = p; p += NX;
    bf16* vhp = p; p += NX;
    bf16* ctxp = p; p += NX;

    cvt_kernel<<<NX / 1024, 256, 0, stream>>>(q,  xq,  (int)NX);
    cvt_kernel<<<NX / 1024, 256, 0, stream>>>(k,  xk,  (int)NX);
    cvt_kernel<<<NX / 1024, 256, 0, stream>>>(v,  xv,  (int)NX);
    cvt_kernel<<<NW / 1024, 256, 0, stream>>>(wq, wqb, (int)NW);
    cvt_kernel<<<NW / 1024, 256, 0, stream>>>(wk, wkb, (int)NW);
    cvt_kernel<<<NW / 1024, 256, 0, stream>>>(wv, wvb, (int)NW);
    cvt_kernel<<<NW / 1024, 256, 0, stream>>>(wo, wob, (int)NW);

    gemm_qkv<<<dim3(MROWS / 128, DM / 128, 3), 256, 0, stream>>>(
        xq, xk, xv, wqb, wkb, wvb, qhp, khp, vhp);

    flash_attn<<<dim3(SEQ / 64, BSZ * HN), 256, 0, stream>>>(qhp, khp, vhp, ctxp);

    gemm_out<<<dim3(MROWS / 128, DM / 128), 256, 0, stream>>>(ctxp, wob, out);
}

// Round 3
// 150.971 us; speedup vs baseline: 1.6529x; 1.6529x over previous
//
#include <hip/hip_runtime.h>

#define DM   768
#define HN   12
#define DKH  64
#define BSZ  2
#define SEQ  2048
#define MROWS (BSZ*SEQ)   // 4096
#define NEGBIG -1.0e9f

typedef __bf16 bf16;
typedef __bf16 bf16x8 __attribute__((ext_vector_type(8)));
typedef __bf16 bf16x4 __attribute__((ext_vector_type(4)));
typedef float  f32x4  __attribute__((ext_vector_type(4)));
typedef unsigned int uint32;

__device__ __forceinline__ void gload_lds16(const void* g, void* l) {
    __builtin_amdgcn_global_load_lds(
        (const __attribute__((address_space(1))) char*)g,
        (__attribute__((address_space(3))) char*)l, 16, 0, 0);
}

// ---------------- fp32 -> bf16 converts (merged) ----------------
__global__ __launch_bounds__(256) void cvt3(const float* __restrict__ a, const float* __restrict__ b,
                                            const float* __restrict__ c,
                                            bf16* __restrict__ x, bf16* __restrict__ y,
                                            bf16* __restrict__ z, int n) {
    const float* s; bf16* d;
    if      (blockIdx.y == 0) { s = a; d = x; }
    else if (blockIdx.y == 1) { s = b; d = y; }
    else                      { s = c; d = z; }
    int i = (blockIdx.x * 256 + threadIdx.x) * 4;
    if (i + 3 < n) {
        float4 v = *(const float4*)(s + i);
        bf16x4 o; o[0] = (bf16)v.x; o[1] = (bf16)v.y; o[2] = (bf16)v.z; o[3] = (bf16)v.w;
        *(bf16x4*)(d + i) = o;
    }
}
__global__ __launch_bounds__(256) void cvt4(const float* __restrict__ a, const float* __restrict__ b,
                                            const float* __restrict__ c, const float* __restrict__ e,
                                            bf16* __restrict__ x, bf16* __restrict__ y,
                                            bf16* __restrict__ z, bf16* __restrict__ u, int n) {
    const float* s; bf16* d;
    if      (blockIdx.y == 0) { s = a; d = x; }
    else if (blockIdx.y == 1) { s = b; d = y; }
    else if (blockIdx.y == 2) { s = c; d = z; }
    else                      { s = e; d = u; }
    int i = (blockIdx.x * 256 + threadIdx.x) * 4;
    if (i + 3 < n) {
        float4 v = *(const float4*)(s + i);
        bf16x4 o; o[0] = (bf16)v.x; o[1] = (bf16)v.y; o[2] = (bf16)v.z; o[3] = (bf16)v.w;
        *(bf16x4*)(d + i) = o;
    }
}

// ---------------- QKV projection GEMM (m97 structure) ----------------
__global__ __launch_bounds__(256) void gemm_qkv(
    const bf16* __restrict__ xq, const bf16* __restrict__ xk, const bf16* __restrict__ xv,
    const bf16* __restrict__ wq, const bf16* __restrict__ wk, const bf16* __restrict__ wv,
    bf16* __restrict__ qh, bf16* __restrict__ kh, bf16* __restrict__ vh)
{
    __shared__ bf16 As[128 * 32];
    __shared__ bf16 Bs[128 * 32];

    const bf16* A; const bf16* Bw; bf16* Out;
    if      (blockIdx.z == 0) { A = xq; Bw = wq; Out = qh; }
    else if (blockIdx.z == 1) { A = xk; Bw = wk; Out = kh; }
    else                      { A = xv; Bw = wv; Out = vh; }

    const int t = threadIdx.x, w = t >> 6, lane = t & 63;
    const int mt = blockIdx.x * 128, nt = blockIdx.y * 128;
    const int wr = (w >> 1) * 64, wc = (w & 1) * 64;

    f32x4 acc[4][4] = {};

    for (int k0 = 0; k0 < DM; k0 += 32) {
        #pragma unroll
        for (int i = 0; i < 2; i++) {
            int c = i * 256 + t;
            int row = c >> 2, col = (c & 3) * 8;
            gload_lds16(A  + (size_t)(mt + row) * DM + k0 + col, (char*)As + c * 16);
            gload_lds16(Bw + (size_t)(nt + row) * DM + k0 + col, (char*)Bs + c * 16);
        }
        asm volatile("s_waitcnt vmcnt(0)" ::: "memory");
        __syncthreads();

        bf16x8 af[4], bfr[4];
        #pragma unroll
        for (int m = 0; m < 4; m++)
            af[m] = *(const bf16x8*)&As[(wr + m * 16 + (lane & 15)) * 32 + (lane >> 4) * 8];
        #pragma unroll
        for (int n = 0; n < 4; n++)
            bfr[n] = *(const bf16x8*)&Bs[(wc + n * 16 + (lane & 15)) * 32 + (lane >> 4) * 8];
        #pragma unroll
        for (int m = 0; m < 4; m++)
            #pragma unroll
            for (int n = 0; n < 4; n++)
                acc[m][n] = __builtin_amdgcn_mfma_f32_16x16x32_bf16(af[m], bfr[n], acc[m][n], 0, 0, 0);
        __syncthreads();
    }

    #pragma unroll
    for (int m = 0; m < 4; m++) {
        #pragma unroll
        for (int n = 0; n < 4; n++) {
            #pragma unroll
            for (int r = 0; r < 4; r++) {
                int gm = mt + wr + m * 16 + (lane >> 4) * 4 + r;
                int gn = nt + wc + n * 16 + (lane & 15);
                int b = gm >> 11, s = gm & 2047, h = gn >> 6, d = gn & 63;
                Out[(((size_t)b * HN + h) * SEQ + s) * DKH + d] = (bf16)acc[m][n][r];
            }
        }
    }
}

// ---------------- output projection GEMM ----------------
__global__ __launch_bounds__(256) void gemm_out(
    const bf16* __restrict__ Actx, const bf16* __restrict__ Bw, float* __restrict__ Out)
{
    __shared__ bf16 As[128 * 32];
    __shared__ bf16 Bs[128 * 32];

    const int t = threadIdx.x, w = t >> 6, lane = t & 63;
    const int mt = blockIdx.x * 128, nt = blockIdx.y * 128;
    const int wr = (w >> 1) * 64, wc = (w & 1) * 64;

    f32x4 acc[4][4] = {};

    for (int k0 = 0; k0 < DM; k0 += 32) {
        #pragma unroll
        for (int i = 0; i < 2; i++) {
            int c = i * 256 + t;
            int row = c >> 2, col = (c & 3) * 8;
            gload_lds16(Actx + (size_t)(mt + row) * DM + k0 + col, (char*)As + c * 16);
            gload_lds16(Bw   + (size_t)(nt + row) * DM + k0 + col, (char*)Bs + c * 16);
        }
        asm volatile("s_waitcnt vmcnt(0)" ::: "memory");
        __syncthreads();

        bf16x8 af[4], bfr[4];
        #pragma unroll
        for (int m = 0; m < 4; m++)
            af[m] = *(const bf16x8*)&As[(wr + m * 16 + (lane & 15)) * 32 + (lane >> 4) * 8];
        #pragma unroll
        for (int n = 0; n < 4; n++)
            bfr[n] = *(const bf16x8*)&Bs[(wc + n * 16 + (lane & 15)) * 32 + (lane >> 4) * 8];
        #pragma unroll
        for (int m = 0; m < 4; m++)
            #pragma unroll
            for (int n = 0; n < 4; n++)
                acc[m][n] = __builtin_amdgcn_mfma_f32_16x16x32_bf16(af[m], bfr[n], acc[m][n], 0, 0, 0);
        __syncthreads();
    }

    #pragma unroll
    for (int m = 0; m < 4; m++) {
        #pragma unroll
        for (int n = 0; n < 4; n++) {
            #pragma unroll
            for (int r = 0; r < 4; r++) {
                int gm = mt + wr + m * 16 + (lane >> 4) * 4 + r;
                int gn = nt + wc + n * 16 + (lane & 15);
                Out[(size_t)gm * DM + gn] = acc[m][n][r];
            }
        }
    }
}

// ---------------- causal flash attention, KVBLK=64 ----------------
// K LDS (per 64x64 tile): LDS chunk (r,s) holds global 16B chunk (r, s^(r&7)).
//   Read K[key][chunk j] at byte key*128 + 16*(j ^ (key&7)).   (m214 swizzle)
// V LDS: Vt[d][key] at element d*72 + (key ^ (((d>>3)&7)<<3)), double-buffered,
//   register-staged transpose (global->reg early, ds_write after compute).
__global__ __launch_bounds__(256) void flash_attn(
    const bf16* __restrict__ qh, const bf16* __restrict__ kh,
    const bf16* __restrict__ vh, bf16* __restrict__ ctx)
{
    __shared__ bf16 Ks[2][4096];     // 8 KB each
    __shared__ bf16 Vt[2][64 * 72];  // 9 KB each
    __shared__ bf16 pl[4][16 * 72];  // per-wave P

    // pair heavy with light q-tiles
    const int qt = (blockIdx.x & 1) ? (31 - (blockIdx.x >> 1)) : (int)(blockIdx.x >> 1);
    const int qb = qt * 64;
    const int bh = blockIdx.y;
    const int t = threadIdx.x, w = t >> 6, lane = t & 63;
    const int g = lane >> 4, lo = lane & 15;
    const size_t base = (size_t)bh * SEQ * DKH;
    const char* khead = (const char*)(kh + base);
    const bf16* vhead = vh + base;

    // K stage: swizzled source byte offsets within a 64x64 tile (dest is linear)
    uint32 koff[2];
    #pragma unroll
    for (int i = 0; i < 2; i++) {
        int c = w * 128 + i * 64 + lane;
        int r = c >> 3, s = c & 7;
        koff[i] = (uint32)(r * 128 + 16 * (s ^ (r & 7)));
    }
    // K read byte offsets (within tile; cg adds *2048)
    const uint32 kr0 = (uint32)(128 * lo + 16 * (g ^ (lo & 7)));
    const uint32 kr1 = kr0 ^ 64;

    // V stage assignment: thread owns keys {vkey, vkey+32}, d in [vd0, vd0+8)
    const int vkey = t >> 3;              // 0..31
    const int vd0  = (t & 7) * 8;
    const int vf   = (vd0 >> 3) & 7;      // swizzle bits for this thread's d-block
    const int swk1 = vkey ^ (vf << 3);
    const int swk2 = (vkey + 32) ^ (vf << 3);

    // Q fragments
    const bf16* qp = qh + base + (size_t)(qb + w * 16 + lo) * DKH + g * 8;
    bf16x8 q0 = *(const bf16x8*)qp;
    bf16x8 q1 = *(const bf16x8*)(qp + 32);

    f32x4 O[4] = {};
    float m_old[4], l_run[4];
    int qi[4];
    #pragma unroll
    for (int r = 0; r < 4; r++) {
        m_old[r] = -1e30f; l_run[r] = 0.0f;
        qi[r] = qb + w * 16 + g * 4 + r;
    }
    bf16* plw = &pl[w][0];

    const int T = qt + 1;

    // prologue: stage tile 0
    {
        #pragma unroll
        for (int i = 0; i < 2; i++)
            gload_lds16(khead + koff[i], (char*)&Ks[0][0] + (w * 128 + i * 64 + lane) * 16);
        bf16x8 va = *(const bf16x8*)(vhead + (size_t)vkey * DKH + vd0);
        bf16x8 vb = *(const bf16x8*)(vhead + (size_t)(vkey + 32) * DKH + vd0);
        asm volatile("s_waitcnt vmcnt(0)" ::: "memory");
        #pragma unroll
        for (int j = 0; j < 8; j++) {
            Vt[0][(vd0 + j) * 72 + swk1] = va[j];
            Vt[0][(vd0 + j) * 72 + swk2] = vb[j];
        }
    }
    __syncthreads();

    bf16x8 vra, vrb;
    for (int it = 0; it < T; ++it) {
        const int par = it & 1, nxt = par ^ 1;
        const bool pf = (it + 1 < T);
        if (pf) {   // issue next tile: K via DMA, V into regs
            const char* ks = khead + (size_t)(it + 1) * 8192;
            #pragma unroll
            for (int i = 0; i < 2; i++)
                gload_lds16(ks + koff[i], (char*)&Ks[nxt][0] + (w * 128 + i * 64 + lane) * 16);
            vra = *(const bf16x8*)(vhead + (size_t)((it + 1) * 64 + vkey) * DKH + vd0);
            vrb = *(const bf16x8*)(vhead + (size_t)((it + 1) * 64 + vkey + 32) * DKH + vd0);
        }

        // ---- QK^T: 16 q-rows x 64 keys ----
        const char* Kp = (const char*)&Ks[par][0];
        f32x4 s[4];
        __builtin_amdgcn_s_setprio(1);
        #pragma unroll
        for (int cg = 0; cg < 4; cg++) {
            bf16x8 kf0 = *(const bf16x8*)(Kp + cg * 2048 + kr0);
            bf16x8 kf1 = *(const bf16x8*)(Kp + cg * 2048 + kr1);
            f32x4 z = {0.0f, 0.0f, 0.0f, 0.0f};
            z = __builtin_amdgcn_mfma_f32_16x16x32_bf16(q0, kf0, z, 0, 0, 0);
            z = __builtin_amdgcn_mfma_f32_16x16x32_bf16(q1, kf1, z, 0, 0, 0);
            s[cg] = z;
        }
        __builtin_amdgcn_s_setprio(0);

        // scale (+ mask only on diagonal tile)
        if (it == T - 1) {
            #pragma unroll
            for (int cg = 0; cg < 4; cg++) {
                int ki = it * 64 + cg * 16 + lo;
                #pragma unroll
                for (int r = 0; r < 4; r++) {
                    float v = s[cg][r] * 0.125f;
                    s[cg][r] = (ki > qi[r]) ? NEGBIG : v;
                }
            }
        } else {
            #pragma unroll
            for (int cg = 0; cg < 4; cg++)
                #pragma unroll
                for (int r = 0; r < 4; r++) s[cg][r] *= 0.125f;
        }

        // online softmax (row spread over the 16-lane lo group)
        float mt_[4];
        #pragma unroll
        for (int r = 0; r < 4; r++)
            mt_[r] = fmaxf(fmaxf(s[0][r], s[1][r]), fmaxf(s[2][r], s[3][r]));
        #pragma unroll
        for (int msk = 1; msk < 16; msk <<= 1)
            #pragma unroll
            for (int r = 0; r < 4; r++) mt_[r] = fmaxf(mt_[r], __shfl_xor(mt_[r], msk, 64));

        float scl[4], rs[4];
        #pragma unroll
        for (int r = 0; r < 4; r++) {
            float mnew = fmaxf(m_old[r], mt_[r]);
            scl[r] = __expf(m_old[r] - mnew);
            m_old[r] = mnew;
            #pragma unroll
            for (int cg = 0; cg < 4; cg++) s[cg][r] = __expf(s[cg][r] - mnew);
            rs[r] = (s[0][r] + s[1][r]) + (s[2][r] + s[3][r]);
        }
        #pragma unroll
        for (int msk = 1; msk < 16; msk <<= 1)
            #pragma unroll
            for (int r = 0; r < 4; r++) rs[r] += __shfl_xor(rs[r], msk, 64);
        #pragma unroll
        for (int r = 0; r < 4; r++) l_run[r] = l_run[r] * scl[r] + rs[r];
        #pragma unroll
        for (int dg = 0; dg < 4; dg++)
            #pragma unroll
            for (int r = 0; r < 4; r++) O[dg][r] *= scl[r];

        // P -> per-wave LDS (C-frag -> A-frag relayout)
        #pragma unroll
        for (int cg = 0; cg < 4; cg++)
            #pragma unroll
            for (int r = 0; r < 4; r++)
                plw[(4 * g + r) * 72 + cg * 16 + lo] = (bf16)s[cg][r];
        asm volatile("s_waitcnt lgkmcnt(0)" ::: "memory");

        // ---- PV ----
        __builtin_amdgcn_s_setprio(1);
        #pragma unroll
        for (int kq = 0; kq < 2; kq++) {
            bf16x8 pa = *(const bf16x8*)&plw[lo * 72 + kq * 32 + 8 * g];
            #pragma unroll
            for (int dblk = 0; dblk < 4; dblk++) {
                int d = dblk * 16 + lo;
                int f = (d >> 3) & 7;
                int kb = (kq * 32 + 8 * g) ^ (f << 3);
                bf16x8 vv = *(const bf16x8*)&Vt[par][d * 72 + kb];
                O[dblk] = __builtin_amdgcn_mfma_f32_16x16x32_bf16(pa, vv, O[dblk], 0, 0, 0);
            }
        }
        __builtin_amdgcn_s_setprio(0);

        asm volatile("s_waitcnt vmcnt(0)" ::: "memory");
        if (pf) {   // write prefetched V regs transposed into next buffer
            #pragma unroll
            for (int j = 0; j < 8; j++) {
                Vt[nxt][(vd0 + j) * 72 + swk1] = vra[j];
                Vt[nxt][(vd0 + j) * 72 + swk2] = vrb[j];
            }
        }
        __syncthreads();
    }

    // epilogue
    float inv[4];
    #pragma unroll
    for (int r = 0; r < 4; r++) inv[r] = 1.0f / l_run[r];
    const int b = bh / HN, h = bh % HN;
    #pragma unroll
    for (int dg = 0; dg < 4; dg++) {
        #pragma unroll
        for (int r = 0; r < 4; r++) {
            int row = qb + w * 16 + g * 4 + r;
            ctx[((size_t)(b * SEQ + row)) * DM + h * DKH + dg * 16 + lo] =
                (bf16)(O[dg][r] * inv[r]);
        }
    }
}

// ---------------- launch ----------------
extern "C" void kernel_launch(void* const* d_in, const int* in_sizes, int n_in,
                              void* d_out, int out_size, void* d_ws, size_t ws_size,
                              hipStream_t stream) {
    const float* q  = (const float*)d_in[0];
    const float* k  = (const float*)d_in[1];
    const float* v  = (const float*)d_in[2];
    const float* wq = (const float*)d_in[4];
    const float* wk = (const float*)d_in[5];
    const float* wv = (const float*)d_in[6];
    const float* wo = (const float*)d_in[7];
    float* out = (float*)d_out;

    const size_t NX = (size_t)MROWS * DM;
    const size_t NW = (size_t)DM * DM;

    bf16* p = (bf16*)d_ws;
    bf16* xq  = p; p += NX;
    bf16* xk  = p; p += NX;
    bf16* xv  = p; p += NX;
    bf16* wqb = p; p += NW;
    bf16* wkb = p; p += NW;
    bf16* wvb = p; p += NW;
    bf16* wob = p; p += NW;
    bf16* qhp = p; p += NX;
    bf16* khp = p; p += NX;
    bf16* vhp = p; p += NX;
    bf16* ctxp = p; p += NX;

    cvt3<<<dim3(NX / 1024, 3), 256, 0, stream>>>(q, k, v, xq, xk, xv, (int)NX);
    cvt4<<<dim3(NW / 1024, 4), 256, 0, stream>>>(wq, wk, wv, wo, wqb, wkb, wvb, wob, (int)NW);

    gemm_qkv<<<dim3(MROWS / 128, DM / 128, 3), 256, 0, stream>>>(
        xq, xk, xv, wqb, wkb, wvb, qhp, khp, vhp);

    flash_attn<<<dim3(SEQ / 64, BSZ * HN), 256, 0, stream>>>(qhp, khp, vhp, ctxp);

    gemm_out<<<dim3(MROWS / 128, DM / 128), 256, 0, stream>>>(ctxp, wob, out);
}

// Round 4
// 120.113 us; speedup vs baseline: 2.0776x; 1.2569x over previous
//
#include <hip/hip_runtime.h>

#define DM   768
#define HN   12
#define DKH  64
#define BSZ  2
#define SEQ  2048
#define MROWS (BSZ*SEQ)   // 4096
#define NEGBIG -1.0e9f

typedef __bf16 bf16;
typedef __bf16 bf16x8 __attribute__((ext_vector_type(8)));
typedef __bf16 bf16x4 __attribute__((ext_vector_type(4)));
typedef float  f32x4  __attribute__((ext_vector_type(4)));
typedef unsigned int uint32;

__device__ __forceinline__ void gload_lds16(const void* g, void* l) {
    __builtin_amdgcn_global_load_lds(
        (const __attribute__((address_space(1))) char*)g,
        (__attribute__((address_space(3))) char*)l, 16, 0, 0);
}

// ---------------- fp32 -> bf16 converts (merged) ----------------
__global__ __launch_bounds__(256) void cvt3(const float* __restrict__ a, const float* __restrict__ b,
                                            const float* __restrict__ c,
                                            bf16* __restrict__ x, bf16* __restrict__ y,
                                            bf16* __restrict__ z, int n) {
    const float* s; bf16* d;
    if      (blockIdx.y == 0) { s = a; d = x; }
    else if (blockIdx.y == 1) { s = b; d = y; }
    else                      { s = c; d = z; }
    int i = (blockIdx.x * 256 + threadIdx.x) * 4;
    if (i + 3 < n) {
        float4 v = *(const float4*)(s + i);
        bf16x4 o; o[0] = (bf16)v.x; o[1] = (bf16)v.y; o[2] = (bf16)v.z; o[3] = (bf16)v.w;
        *(bf16x4*)(d + i) = o;
    }
}
__global__ __launch_bounds__(256) void cvt4(const float* __restrict__ a, const float* __restrict__ b,
                                            const float* __restrict__ c, const float* __restrict__ e,
                                            bf16* __restrict__ x, bf16* __restrict__ y,
                                            bf16* __restrict__ z, bf16* __restrict__ u, int n) {
    const float* s; bf16* d;
    if      (blockIdx.y == 0) { s = a; d = x; }
    else if (blockIdx.y == 1) { s = b; d = y; }
    else if (blockIdx.y == 2) { s = c; d = z; }
    else                      { s = e; d = u; }
    int i = (blockIdx.x * 256 + threadIdx.x) * 4;
    if (i + 3 < n) {
        float4 v = *(const float4*)(s + i);
        bf16x4 o; o[0] = (bf16)v.x; o[1] = (bf16)v.y; o[2] = (bf16)v.z; o[3] = (bf16)v.w;
        *(bf16x4*)(d + i) = o;
    }
}

// ---------------- QKV projection GEMM (m97 structure) ----------------
// Q,K out: [b,h,s,d]. V out: TRANSPOSED [b,h,d,s] (bf16x4 stores over s).
__global__ __launch_bounds__(256) void gemm_qkv(
    const bf16* __restrict__ xq, const bf16* __restrict__ xk, const bf16* __restrict__ xv,
    const bf16* __restrict__ wq, const bf16* __restrict__ wk, const bf16* __restrict__ wv,
    bf16* __restrict__ qh, bf16* __restrict__ kh, bf16* __restrict__ vt)
{
    __shared__ bf16 As[128 * 32];
    __shared__ bf16 Bs[128 * 32];

    const bf16* A; const bf16* Bw; bf16* Out;
    if      (blockIdx.z == 0) { A = xq; Bw = wq; Out = qh; }
    else if (blockIdx.z == 1) { A = xk; Bw = wk; Out = kh; }
    else                      { A = xv; Bw = wv; Out = vt; }
    const bool vout = (blockIdx.z == 2);

    const int t = threadIdx.x, w = t >> 6, lane = t & 63;
    const int mt = blockIdx.x * 128, nt = blockIdx.y * 128;
    const int wr = (w >> 1) * 64, wc = (w & 1) * 64;

    f32x4 acc[4][4] = {};

    for (int k0 = 0; k0 < DM; k0 += 32) {
        #pragma unroll
        for (int i = 0; i < 2; i++) {
            int c = i * 256 + t;
            int row = c >> 2, col = (c & 3) * 8;
            gload_lds16(A  + (size_t)(mt + row) * DM + k0 + col, (char*)As + c * 16);
            gload_lds16(Bw + (size_t)(nt + row) * DM + k0 + col, (char*)Bs + c * 16);
        }
        asm volatile("s_waitcnt vmcnt(0)" ::: "memory");
        __syncthreads();

        bf16x8 af[4], bfr[4];
        #pragma unroll
        for (int m = 0; m < 4; m++)
            af[m] = *(const bf16x8*)&As[(wr + m * 16 + (lane & 15)) * 32 + (lane >> 4) * 8];
        #pragma unroll
        for (int n = 0; n < 4; n++)
            bfr[n] = *(const bf16x8*)&Bs[(wc + n * 16 + (lane & 15)) * 32 + (lane >> 4) * 8];
        #pragma unroll
        for (int m = 0; m < 4; m++)
            #pragma unroll
            for (int n = 0; n < 4; n++)
                acc[m][n] = __builtin_amdgcn_mfma_f32_16x16x32_bf16(af[m], bfr[n], acc[m][n], 0, 0, 0);
        __syncthreads();
    }

    if (!vout) {
        #pragma unroll
        for (int m = 0; m < 4; m++) {
            #pragma unroll
            for (int n = 0; n < 4; n++) {
                #pragma unroll
                for (int r = 0; r < 4; r++) {
                    int gm = mt + wr + m * 16 + (lane >> 4) * 4 + r;
                    int gn = nt + wc + n * 16 + (lane & 15);
                    int b = gm >> 11, s = gm & 2047, h = gn >> 6, d = gn & 63;
                    Out[(((size_t)b * HN + h) * SEQ + s) * DKH + d] = (bf16)acc[m][n][r];
                }
            }
        }
    } else {
        #pragma unroll
        for (int m = 0; m < 4; m++) {
            #pragma unroll
            for (int n = 0; n < 4; n++) {
                int gm = mt + wr + m * 16 + (lane >> 4) * 4;   // s, 4-aligned
                int gn = nt + wc + n * 16 + (lane & 15);
                int b = gm >> 11, s0 = gm & 2047, h = gn >> 6, d = gn & 63;
                bf16x4 pk;
                #pragma unroll
                for (int r = 0; r < 4; r++) pk[r] = (bf16)acc[m][n][r];
                *(bf16x4*)&Out[(((size_t)b * HN + h) * DKH + d) * SEQ + s0] = pk;
            }
        }
    }
}

// ---------------- output projection GEMM ----------------
__global__ __launch_bounds__(256) void gemm_out(
    const bf16* __restrict__ Actx, const bf16* __restrict__ Bw, float* __restrict__ Out)
{
    __shared__ bf16 As[128 * 32];
    __shared__ bf16 Bs[128 * 32];

    const int t = threadIdx.x, w = t >> 6, lane = t & 63;
    const int mt = blockIdx.x * 128, nt = blockIdx.y * 128;
    const int wr = (w >> 1) * 64, wc = (w & 1) * 64;

    f32x4 acc[4][4] = {};

    for (int k0 = 0; k0 < DM; k0 += 32) {
        #pragma unroll
        for (int i = 0; i < 2; i++) {
            int c = i * 256 + t;
            int row = c >> 2, col = (c & 3) * 8;
            gload_lds16(Actx + (size_t)(mt + row) * DM + k0 + col, (char*)As + c * 16);
            gload_lds16(Bw   + (size_t)(nt + row) * DM + k0 + col, (char*)Bs + c * 16);
        }
        asm volatile("s_waitcnt vmcnt(0)" ::: "memory");
        __syncthreads();

        bf16x8 af[4], bfr[4];
        #pragma unroll
        for (int m = 0; m < 4; m++)
            af[m] = *(const bf16x8*)&As[(wr + m * 16 + (lane & 15)) * 32 + (lane >> 4) * 8];
        #pragma unroll
        for (int n = 0; n < 4; n++)
            bfr[n] = *(const bf16x8*)&Bs[(wc + n * 16 + (lane & 15)) * 32 + (lane >> 4) * 8];
        #pragma unroll
        for (int m = 0; m < 4; m++)
            #pragma unroll
            for (int n = 0; n < 4; n++)
                acc[m][n] = __builtin_amdgcn_mfma_f32_16x16x32_bf16(af[m], bfr[n], acc[m][n], 0, 0, 0);
        __syncthreads();
    }

    #pragma unroll
    for (int m = 0; m < 4; m++) {
        #pragma unroll
        for (int n = 0; n < 4; n++) {
            #pragma unroll
            for (int r = 0; r < 4; r++) {
                int gm = mt + wr + m * 16 + (lane >> 4) * 4 + r;
                int gn = nt + wc + n * 16 + (lane & 15);
                Out[(size_t)gm * DM + gn] = acc[m][n][r];
            }
        }
    }
}

// ---------------- causal flash attention, KVBLK=64, swapped QK^T ----------------
// K head: [b,h,s,d] (row = key, 128B). V head: [b,h,d,s] (row = d, key-contig).
// Both DMA-staged into 64x64 swizzled LDS tiles: LDS chunk (r,s) holds global
// chunk (r, s^(r&7)); read chunk j of row r at byte r*128 + 16*(j^(r&7)).
// QK^T computed swapped (S^T = K·Q^T): lane holds S^T[key=16cg+4g+r][q=lo].
__global__ __launch_bounds__(256) void flash_attn(
    const bf16* __restrict__ qh, const bf16* __restrict__ kh,
    const bf16* __restrict__ vt, bf16* __restrict__ ctx)
{
    __shared__ bf16 Ks[2][4096];     // 8 KB each
    __shared__ bf16 Vs[2][4096];     // 8 KB each
    __shared__ bf16 pl[4][16 * 72];  // per-wave P [q=16][key stride 72]

    // pair heavy with light q-tiles
    const int qt = (blockIdx.x & 1) ? (31 - (blockIdx.x >> 1)) : (int)(blockIdx.x >> 1);
    const int qb = qt * 64;
    const int bh = blockIdx.y;
    const int t = threadIdx.x, w = t >> 6, lane = t & 63;
    const int g = lane >> 4, lo = lane & 15;
    const size_t base = (size_t)bh * SEQ * DKH;
    const char* khead = (const char*)(kh + base);
    const char* vhead = (const char*)(vt + base);

    // DMA source byte offsets within a tile (dest is linear chunk*16)
    uint32 koff[2], voff[2];
    #pragma unroll
    for (int i = 0; i < 2; i++) {
        int c = w * 128 + i * 64 + lane;
        int r = c >> 3, s = c & 7;
        int sw = s ^ (r & 7);
        koff[i] = (uint32)(r * 128  + 16 * sw);   // K: row stride 128 B
        voff[i] = (uint32)(r * 4096 + 16 * sw);   // V^T: row stride SEQ*2 B
    }
    // read byte offsets (within tile)
    const uint32 kr0 = (uint32)(128 * lo + 16 * (g ^ (lo & 7)));        // K row=key=lo(+16cg)
    const uint32 kr1 = kr0 ^ 64;                                         // d half 1

    // Q fragments (B-operand of swapped QK^T)
    const bf16* qp = qh + base + (size_t)(qb + w * 16 + lo) * DKH + g * 8;
    bf16x8 q0 = *(const bf16x8*)qp;
    bf16x8 q1 = *(const bf16x8*)(qp + 32);

    f32x4 O[4] = {};
    float m_old = -1e30f, l_run = 0.0f;   // stats for q = lo
    const int qrow = qb + w * 16 + lo;
    bf16* plw = &pl[w][0];

    const int T = qt + 1;

    // prologue: stage tile 0 (K + V)
    #pragma unroll
    for (int i = 0; i < 2; i++) {
        int c16 = (w * 128 + i * 64 + lane) * 16;
        gload_lds16(khead + koff[i], (char*)&Ks[0][0] + c16);
        gload_lds16(vhead + voff[i], (char*)&Vs[0][0] + c16);
    }
    asm volatile("s_waitcnt vmcnt(0)" ::: "memory");
    __syncthreads();

    for (int it = 0; it < T; ++it) {
        const int par = it & 1, nxt = par ^ 1;
        if (it + 1 < T) {   // stage next tile (stays in flight across compute)
            const char* ks = khead + (size_t)(it + 1) * 8192;   // 64 keys * 128 B
            const char* vs = vhead + (size_t)(it + 1) * 128;    // 64 keys * 2 B
            #pragma unroll
            for (int i = 0; i < 2; i++) {
                int c16 = (w * 128 + i * 64 + lane) * 16;
                gload_lds16(ks + koff[i], (char*)&Ks[nxt][0] + c16);
                gload_lds16(vs + voff[i], (char*)&Vs[nxt][0] + c16);
            }
        }

        // ---- swapped QK^T: S^T[key][q], 64 keys x 16 q-rows ----
        const char* Kp = (const char*)&Ks[par][0];
        f32x4 s[4];
        __builtin_amdgcn_s_setprio(1);
        #pragma unroll
        for (int cg = 0; cg < 4; cg++) {
            bf16x8 kf0 = *(const bf16x8*)(Kp + cg * 2048 + kr0);
            bf16x8 kf1 = *(const bf16x8*)(Kp + cg * 2048 + kr1);
            f32x4 z = {0.0f, 0.0f, 0.0f, 0.0f};
            z = __builtin_amdgcn_mfma_f32_16x16x32_bf16(kf0, q0, z, 0, 0, 0);
            z = __builtin_amdgcn_mfma_f32_16x16x32_bf16(kf1, q1, z, 0, 0, 0);
            s[cg] = z;
        }
        __builtin_amdgcn_s_setprio(0);

        // scale (+ mask only on diagonal tile); lane's 16 values all q = lo
        if (it == T - 1) {
            #pragma unroll
            for (int cg = 0; cg < 4; cg++)
                #pragma unroll
                for (int r = 0; r < 4; r++) {
                    int ki = it * 64 + cg * 16 + 4 * g + r;
                    float v = s[cg][r] * 0.125f;
                    s[cg][r] = (ki > qrow) ? NEGBIG : v;
                }
        } else {
            #pragma unroll
            for (int cg = 0; cg < 4; cg++)
                #pragma unroll
                for (int r = 0; r < 4; r++) s[cg][r] *= 0.125f;
        }

        // ---- online softmax: in-lane reduce + 2 shfl_xor rounds ----
        float mx = fmaxf(fmaxf(fmaxf(s[0][0], s[0][1]), fmaxf(s[0][2], s[0][3])),
                         fmaxf(fmaxf(s[1][0], s[1][1]), fmaxf(s[1][2], s[1][3])));
        mx = fmaxf(mx, fmaxf(fmaxf(fmaxf(s[2][0], s[2][1]), fmaxf(s[2][2], s[2][3])),
                             fmaxf(fmaxf(s[3][0], s[3][1]), fmaxf(s[3][2], s[3][3]))));
        mx = fmaxf(mx, __shfl_xor(mx, 16, 64));
        mx = fmaxf(mx, __shfl_xor(mx, 32, 64));

        float mnew = fmaxf(m_old, mx);
        float scl  = __expf(m_old - mnew);
        m_old = mnew;
        float rs = 0.0f;
        #pragma unroll
        for (int cg = 0; cg < 4; cg++)
            #pragma unroll
            for (int r = 0; r < 4; r++) {
                s[cg][r] = __expf(s[cg][r] - mnew);
                rs += s[cg][r];
            }
        rs += __shfl_xor(rs, 16, 64);
        rs += __shfl_xor(rs, 32, 64);
        l_run = l_run * scl + rs;

        // O rescale: O rows are q = 4g+r -> fetch scl from lane 4g+r
        float scl4[4];
        #pragma unroll
        for (int r = 0; r < 4; r++) scl4[r] = __shfl(scl, 4 * g + r, 64);
        #pragma unroll
        for (int dg = 0; dg < 4; dg++)
            #pragma unroll
            for (int r = 0; r < 4; r++) O[dg][r] *= scl4[r];

        // P -> per-wave LDS: P[q=lo][key], r-consecutive keys pack to b64
        #pragma unroll
        for (int cg = 0; cg < 4; cg++) {
            bf16x4 pk;
            #pragma unroll
            for (int r = 0; r < 4; r++) pk[r] = (bf16)s[cg][r];
            *(bf16x4*)&plw[lo * 72 + cg * 16 + 4 * g] = pk;
        }
        asm volatile("s_waitcnt lgkmcnt(0)" ::: "memory");
        __builtin_amdgcn_sched_barrier(0);

        // ---- PV: O[q][d] += P[q][k] V[k][d], B-frag from V^T tile ----
        const char* Vp = (const char*)&Vs[par][0];
        __builtin_amdgcn_s_setprio(1);
        #pragma unroll
        for (int kq = 0; kq < 2; kq++) {
            bf16x8 pa = *(const bf16x8*)&plw[lo * 72 + kq * 32 + 8 * g];
            #pragma unroll
            for (int dblk = 0; dblk < 4; dblk++) {
                int row = dblk * 16 + lo;   // d
                bf16x8 vv = *(const bf16x8*)(Vp + row * 128 + 16 * ((4 * kq + g) ^ (lo & 7)));
                O[dblk] = __builtin_amdgcn_mfma_f32_16x16x32_bf16(pa, vv, O[dblk], 0, 0, 0);
            }
        }
        __builtin_amdgcn_s_setprio(0);

        asm volatile("s_waitcnt vmcnt(0)" ::: "memory");
        __syncthreads();
    }

    // epilogue: normalize, store ctx [B,S,768] bf16
    float inv4[4];
    #pragma unroll
    for (int r = 0; r < 4; r++) inv4[r] = 1.0f / __shfl(l_run, 4 * g + r, 64);
    const int b = bh / HN, h = bh % HN;
    #pragma unroll
    for (int dg = 0; dg < 4; dg++) {
        #pragma unroll
        for (int r = 0; r < 4; r++) {
            int row = qb + w * 16 + g * 4 + r;
            ctx[((size_t)(b * SEQ + row)) * DM + h * DKH + dg * 16 + lo] =
                (bf16)(O[dg][r] * inv4[r]);
        }
    }
}

// ---------------- launch ----------------
extern "C" void kernel_launch(void* const* d_in, const int* in_sizes, int n_in,
                              void* d_out, int out_size, void* d_ws, size_t ws_size,
                              hipStream_t stream) {
    const float* q  = (const float*)d_in[0];
    const float* k  = (const float*)d_in[1];
    const float* v  = (const float*)d_in[2];
    const float* wq = (const float*)d_in[4];
    const float* wk = (const float*)d_in[5];
    const float* wv = (const float*)d_in[6];
    const float* wo = (const float*)d_in[7];
    float* out = (float*)d_out;

    const size_t NX = (size_t)MROWS * DM;
    const size_t NW = (size_t)DM * DM;

    bf16* p = (bf16*)d_ws;
    bf16* xq  = p; p += NX;
    bf16* xk  = p; p += NX;
    bf16* xv  = p; p += NX;
    bf16* wqb = p; p += NW;
    bf16* wkb = p; p += NW;
    bf16* wvb = p; p += NW;
    bf16* wob = p; p += NW;
    bf16* qhp = p; p += NX;
    bf16* khp = p; p += NX;
    bf16* vtp = p; p += NX;   // V^T heads [b,h,d,s]
    bf16* ctxp = p; p += NX;

    cvt3<<<dim3(NX / 1024, 3), 256, 0, stream>>>(q, k, v, xq, xk, xv, (int)NX);
    cvt4<<<dim3(NW / 1024, 4), 256, 0, stream>>>(wq, wk, wv, wo, wqb, wkb, wvb, wob, (int)NW);

    gemm_qkv<<<dim3(MROWS / 128, DM / 128, 3), 256, 0, stream>>>(
        xq, xk, xv, wqb, wkb, wvb, qhp, khp, vtp);

    flash_attn<<<dim3(SEQ / 64, BSZ * HN), 256, 0, stream>>>(qhp, khp, vtp, ctxp);

    gemm_out<<<dim3(MROWS / 128, DM / 128), 256, 0, stream>>>(ctxp, wob, out);
}